// Round 1
// baseline (250.425 us; speedup 1.0000x reference)
//
#include <hip/hip_runtime.h>

#define NPIX (512 * 512)   // 262144
#define NB 32
#define NK 4
#define CHUNKS 64
#define TPB 256
#define CHUNK_ELEMS (NPIX / CHUNKS)          // 4096
#define V4_ITERS (CHUNK_ELEMS / (TPB * 4))   // 4

// ws layout (floats):
// [0..127]   focal_sum  (b*4+k)
// [128..255] p_sum
// [256..383] inter
// [384..511] m_sum
// [512..639] mi
// [640..671] t_sum (per b)
#define WS_FLOATS 672

__global__ __launch_bounds__(TPB) void sam_loss_pass1(
    const float* __restrict__ x, const float* __restrict__ t,
    float* __restrict__ ws) {
  const int blk = blockIdx.x;
  const int b = blk / CHUNKS;
  const int c = blk % CHUNKS;

  const float4* __restrict__ t4 =
      (const float4*)(t + (size_t)b * NPIX + (size_t)c * CHUNK_ELEMS);
  const float* __restrict__ xb =
      x + (size_t)b * NK * NPIX + (size_t)c * CHUNK_ELEMS;

  float fs[NK] = {0.f, 0.f, 0.f, 0.f};
  float ps[NK] = {0.f, 0.f, 0.f, 0.f};
  float is[NK] = {0.f, 0.f, 0.f, 0.f};
  float ms[NK] = {0.f, 0.f, 0.f, 0.f};
  float mis[NK] = {0.f, 0.f, 0.f, 0.f};
  float ts = 0.f;

  for (int it = 0; it < V4_ITERS; ++it) {
    const int i = it * TPB + threadIdx.x;
    const float4 tv = t4[i];
    const float tt[4] = {tv.x, tv.y, tv.z, tv.w};
    ts += (tv.x + tv.y) + (tv.z + tv.w);
#pragma unroll
    for (int k = 0; k < NK; ++k) {
      const float4 xv = ((const float4*)(xb + (size_t)k * NPIX))[i];
      const float xx[4] = {xv.x, xv.y, xv.z, xv.w};
#pragma unroll
      for (int j = 0; j < 4; ++j) {
        const float xf = xx[j];
        const float tf = tt[j];
        const float ax = fabsf(xf);
        const float e = __expf(-ax);                       // exp(-|x|) in (0,1]
        const float r = __builtin_amdgcn_rcpf(1.0f + e);   // 1/(1+e)
        const float l1 = __logf(1.0f + e);                 // log(1+e)
        const bool pos = xf >= 0.0f;
        const float sp_pos = (pos ? xf : 0.0f) + l1;   // softplus(x)
        const float sp_neg = (pos ? 0.0f : -xf) + l1;  // softplus(-x)
        const float s_p = pos ? r : e * r;  // sigmoid(x)
        const float s_n = pos ? e * r : r;  // sigmoid(-x) = 1 - sigmoid(x)
        const bool tpos = tf != 0.0f;       // targets are exactly 0.0 or 1.0
        const float bce = tpos ? sp_neg : sp_pos;
        const float om = tpos ? s_n : s_p;  // 1 - exp(-bce)
        fs[k] += om * om * bce;
        ps[k] += s_p;
        if (tpos) is[k] += s_p;
        if (pos) {
          ms[k] += 1.0f;
          if (tpos) mis[k] += 1.0f;
        }
      }
    }
  }

  // thread -> wave -> block -> global reduction of 21 values
  float vals[21];
#pragma unroll
  for (int k = 0; k < NK; ++k) {
    vals[k] = fs[k];
    vals[4 + k] = ps[k];
    vals[8 + k] = is[k];
    vals[12 + k] = ms[k];
    vals[16 + k] = mis[k];
  }
  vals[20] = ts;

  __shared__ float red[TPB / 64][21];
  const int lane = threadIdx.x & 63;
  const int wid = threadIdx.x >> 6;
#pragma unroll
  for (int j = 0; j < 21; ++j) {
    float v = vals[j];
#pragma unroll
    for (int off = 32; off > 0; off >>= 1) v += __shfl_down(v, off, 64);
    if (lane == 0) red[wid][j] = v;
  }
  __syncthreads();
  if (threadIdx.x < 21) {
    const int j = threadIdx.x;
    float v = red[0][j] + red[1][j] + red[2][j] + red[3][j];
    int off;
    if (j < 20) {
      const int g = j >> 2;
      const int k = j & 3;
      off = g * (NB * NK) + b * NK + k;
    } else {
      off = 5 * (NB * NK) + b;
    }
    atomicAdd(ws + off, v);
  }
}

__global__ __launch_bounds__(64) void sam_loss_pass2(
    const float* __restrict__ ws, const float* __restrict__ ious,
    float* __restrict__ out) {
  const float AREA_LO[4] = {0.04f, 0.0f, 0.01f, 0.16f};
  const float AREA_HI[4] = {0.64f, 0.04f, 0.25f, 1.0f};
  const float S = 1e-4f;
  const int lane = threadIdx.x;

  float pf = 0.f, pd = 0.f, pi = 0.f, sv = 0.f;
  if (lane < NB) {
    const int b = lane;
    const float tsum = ws[5 * (NB * NK) + b];
    const float ratio = tsum / (float)NPIX;
    float cnt = 0.f, sf = 0.f, sd = 0.f, si = 0.f;
#pragma unroll
    for (int k = 0; k < NK; ++k) {
      const bool valid = (ratio > AREA_LO[k]) && (ratio < AREA_HI[k]);
      if (valid) {
        const int idx = b * NK + k;
        const float focal = 0.8f * ws[idx] / (float)NPIX;
        const float psum = ws[1 * (NB * NK) + idx];
        const float inter = ws[2 * (NB * NK) + idx];
        const float msum = ws[3 * (NB * NK) + idx];
        const float mi = ws[4 * (NB * NK) + idx];
        const float dice = 1.0f - (2.0f * inter + S) / (psum + tsum + S);
        const float iou_gt = (mi + S) / (msum + tsum - mi + S);
        const float d = ious[idx] - iou_gt;
        cnt += 1.0f;
        sf += focal;
        sd += dice;
        si += d * d;
      }
    }
    if (cnt > 0.f) {
      pf = sf / cnt;
      pd = sd / cnt;
      pi = si / cnt;
      sv = 1.0f;
    }
  }
#pragma unroll
  for (int off = 32; off > 0; off >>= 1) {
    pf += __shfl_down(pf, off, 64);
    pd += __shfl_down(pd, off, 64);
    pi += __shfl_down(pi, off, 64);
    sv += __shfl_down(sv, off, 64);
  }
  if (lane == 0) {
    const float inv = sv > 0.f ? 1.0f / sv : 1.0f;
    out[0] = 20.0f * pf * inv;
    out[1] = pd * inv;
    out[2] = pi * inv;
  }
}

extern "C" void kernel_launch(void* const* d_in, const int* in_sizes, int n_in,
                              void* d_out, int out_size, void* d_ws,
                              size_t ws_size, hipStream_t stream) {
  const float* pred_masks = (const float*)d_in[0];
  const float* pred_ious = (const float*)d_in[1];
  const float* targets = (const float*)d_in[2];
  float* out = (float*)d_out;
  float* ws = (float*)d_ws;

  hipMemsetAsync(ws, 0, WS_FLOATS * sizeof(float), stream);
  sam_loss_pass1<<<NB * CHUNKS, TPB, 0, stream>>>(pred_masks, targets, ws);
  sam_loss_pass2<<<1, 64, 0, stream>>>(ws, pred_ious, out);
}